// Round 2
// baseline (1904.037 us; speedup 1.0000x reference)
//
#include <hip/hip_runtime.h>
#include <math.h>

#define NT  40000   // total nodes (N*V)
#define EDG 640000  // edges

__device__ __forceinline__ float eluf(float v){ return v > 0.f ? v : expm1f(v); }

// ---------------------------------------------------------------- init: zero deg + cursor
__global__ void k_init(int* __restrict__ deg, int* __restrict__ cursor){
  int i = blockIdx.x*256 + threadIdx.x;
  if (i < NT){ deg[i] = 0; cursor[i] = 0; }
}

// ---------------------------------------------------------------- encoder: x[NT,2] -> h_flat[NT,64], h_flatT[64,NT]
__global__ __launch_bounds__(256) void k_encoder(
    const float* __restrict__ x,
    const float* __restrict__ w0, const float* __restrict__ b0,
    const float* __restrict__ w1, const float* __restrict__ b1,
    const float* __restrict__ w2, const float* __restrict__ b2,
    float* __restrict__ h_flat, float* __restrict__ h_flatT)
{
  int n = blockIdx.x*256 + threadIdx.x;
  bool ok = n < NT;
  int nn = ok ? n : 0;
  float x0 = x[(size_t)nn*2+0], x1 = x[(size_t)nn*2+1];
  float h1[16];
#pragma unroll
  for (int o=0;o<16;o++) h1[o] = eluf(b0[o] + w0[o*2+0]*x0 + w0[o*2+1]*x1);
  float h2[32];
#pragma unroll
  for (int o=0;o<32;o++){
    float a = b1[o];
#pragma unroll
    for (int c=0;c<16;c++) a = fmaf(w1[o*16+c], h1[c], a);
    h2[o] = eluf(a);
  }
#pragma unroll
  for (int o=0;o<64;o++){
    float a = b2[o];
#pragma unroll
    for (int c=0;c<32;c++) a = fmaf(w2[o*32+c], h2[c], a);
    float h = eluf(a);
    if (ok){ h_flat[(size_t)n*64+o] = h; h_flatT[(size_t)o*NT+n] = h; }
  }
}

// ---------------------------------------------------------------- degree count
__global__ void k_count(const int* __restrict__ ei, int* __restrict__ deg){
  int e = blockIdx.x*256 + threadIdx.x;
  if (e < EDG) atomicAdd(&deg[ei[EDG+e]], 1);
}

// ---------------------------------------------------------------- exclusive scan -> rowptr, deg_inv
__global__ __launch_bounds__(1024) void k_scan(
    const int* __restrict__ deg, int* __restrict__ rowptr, float* __restrict__ deg_inv)
{
  __shared__ int sums[1024];
  const int t = threadIdx.x;
  const int base = t*40;
  int s = 0;
  for (int i=0;i<40;i++){ int idx = base+i; if (idx < NT) s += deg[idx]; }
  sums[t] = s; __syncthreads();
  for (int off=1; off<1024; off<<=1){
    int v = (t >= off) ? sums[t-off] : 0;
    __syncthreads();
    sums[t] += v;
    __syncthreads();
  }
  int run = (t==0) ? 0 : sums[t-1];
  for (int i=0;i<40;i++){
    int idx = base+i;
    if (idx < NT){
      rowptr[idx] = run;
      int d = deg[idx];
      run += d;
      deg_inv[idx] = 1.0f / fmaxf((float)d, 1.0f);
    }
  }
  if (t == 1023) rowptr[NT] = run;
}

// ---------------------------------------------------------------- CSR fill: meta = {f0,f1,f2, src<<3|k0pack}
__global__ void k_fill(const int* __restrict__ ei, const float* __restrict__ attr,
                       const int* __restrict__ rowptr, int* __restrict__ cursor,
                       float4* __restrict__ meta)
{
  int e = blockIdx.x*256 + threadIdx.x;
  if (e >= EDG) return;
  int src = ei[e], dst = ei[EDG+e];
  float v0 = attr[(size_t)e*3+0]*2.f, v1 = attr[(size_t)e*3+1]*2.f, v2 = attr[(size_t)e*3+2]*2.f;
  float k00 = fminf(fmaxf(floorf(v0), 0.f), 1.f);
  float k01 = fminf(fmaxf(floorf(v1), 0.f), 1.f);
  float k02 = fminf(fmaxf(floorf(v2), 0.f), 1.f);
  int kp = ((int)k00)*4 + ((int)k01)*2 + (int)k02;
  float f0 = v0-k00, f1 = v1-k01, f2 = v2-k02;
  int pos = rowptr[dst] + atomicAdd(&cursor[dst], 1);
  meta[pos] = make_float4(f0, f1, f2, __int_as_float((src<<3) | kp));
}

// ---------------------------------------------------------------- gather: per-node reg acc for flats [KLO,KHI) -> accT[(flat-KLO)*64+c][node]
template<int KLO, int KHI>
__global__ __launch_bounds__(256) void k_gather(
    const float4* __restrict__ meta,
    const int* __restrict__ rowptr,
    const float* __restrict__ deg_inv,
    const float* __restrict__ h_flat,
    float* __restrict__ accT)
{
  constexpr int KCH = KHI - KLO;     // 9
  constexpr int J0  = KLO / 9;       // dim-0 slab index
  __shared__ float stash[KCH*64*17]; // [row=k*64+c][16 nodes +1 pad]
  const int wid = threadIdx.x>>6, lane = threadIdx.x&63;
  for (int s4=0; s4<4; s4++){
    const int nl = wid*4 + s4;
    const int n  = blockIdx.x*16 + nl;
    float acc[KCH];
#pragma unroll
    for (int k=0;k<KCH;k++) acc[k] = 0.f;
    const int beg = rowptr[n], end = rowptr[n+1];
    for (int jb = beg; jb < end; jb += 16){
      const int bn = end - jb;  // >=1
      float4 mb[16];
#pragma unroll
      for (int i=0;i<16;i++) mb[i] = meta[ (i < bn) ? (jb+i) : jb ];
      float xb[16];
#pragma unroll
      for (int i=0;i<16;i++){
        const int pk  = __float_as_int(mb[i].w);
        const int k00 = (pk>>2)&1;
        const bool contrib = (J0 - k00 == 0) || (J0 - k00 == 1);
        xb[i] = contrib ? h_flat[(size_t)(pk>>3)*64 + lane] : 0.f;
      }
#pragma unroll
      for (int i=0;i<16;i++){
        if (i >= bn) break;
        const int pk  = __float_as_int(mb[i].w);
        const int k0p = pk & 7;
        const int k00 = (k0p>>2)&1;
        if ((J0 - k00) < 0 || (J0 - k00) > 1) continue;
        const float xj = xb[i];
        const float f0 = mb[i].x, f1 = mb[i].y, f2 = mb[i].z;
        const float u0 = 1.f-f0, u1 = 1.f-f1, u2 = 1.f-f2;
#define CORNER(K00,K01,K02,B0,B1,B2) { \
        constexpr int flat = (K00+B0)*9 + (K01+B1)*3 + (K02+B2); \
        if constexpr (flat >= KLO && flat < KHI) \
          acc[flat-KLO] = fmaf(((B0)?f0:u0)*((B1)?f1:u1)*((B2)?f2:u2), xj, acc[flat-KLO]); }
#define CASE8(K00,K01,K02) \
        CORNER(K00,K01,K02,0,0,0) CORNER(K00,K01,K02,0,0,1) \
        CORNER(K00,K01,K02,0,1,0) CORNER(K00,K01,K02,0,1,1) \
        CORNER(K00,K01,K02,1,0,0) CORNER(K00,K01,K02,1,0,1) \
        CORNER(K00,K01,K02,1,1,0) CORNER(K00,K01,K02,1,1,1)
        switch (k0p){
          case 0: CASE8(0,0,0) break;
          case 1: CASE8(0,0,1) break;
          case 2: CASE8(0,1,0) break;
          case 3: CASE8(0,1,1) break;
          case 4: CASE8(1,0,0) break;
          case 5: CASE8(1,0,1) break;
          case 6: CASE8(1,1,0) break;
          case 7: CASE8(1,1,1) break;
        }
#undef CORNER
#undef CASE8
      }
    }
    const float dinv = deg_inv[n];
#pragma unroll
    for (int k=0;k<KCH;k++)
      stash[(k*64+lane)*17 + nl] = acc[k]*dinv;
  }
  __syncthreads();
  // flush: KCH*64 rows x 16 nodes, full-64B-line coalesced global stores
  for (int idx = threadIdx.x; idx < KCH*64*4; idx += 256){
    const int r = idx>>2, q = idx&3;
    float4 v;
    v.x = stash[r*17 + 4*q+0];
    v.y = stash[r*17 + 4*q+1];
    v.z = stash[r*17 + 4*q+2];
    v.w = stash[r*17 + 4*q+3];
    *(float4*)&accT[(size_t)r*NT + blockIdx.x*16 + 4*q] = v;
  }
}

// ---------------------------------------------------------------- contraction: node-per-lane, W rows broadcast, 4-way K split
template<int PASS>
__global__ __launch_bounds__(256) void k_gemm(
    const float* __restrict__ accT,
    const float* __restrict__ h_flatT,
    const float* __restrict__ sp_w,
    const float* __restrict__ sp_root,
    const float* __restrict__ sp_bias,
    float* __restrict__ out_sp)
{
  __shared__ float red[2*4096];
  const int wid = threadIdx.x>>6, lane = threadIdx.x&63;
  const int n = blockIdx.x*64 + lane;   // grid 625 -> exact
  float acc[64];
#pragma unroll
  for (int o=0;o<64;o++) acc[o] = 0.f;
  constexpr int NK  = (PASS==2) ? 640 : 576;
  constexpr int NKW = NK/4;
  const int kb = wid*NKW;
  const float* wbase = sp_w + (size_t)PASS*576*64;
#pragma unroll 4
  for (int kc = kb; kc < kb+NKW; kc++){
    float a; const float* wr;
    if (PASS==2 && kc >= 576){
      a  = h_flatT[(size_t)(kc-576)*NT + n];
      wr = sp_root + (size_t)(kc-576)*64;
    } else {
      a  = accT[(size_t)kc*NT + n];
      wr = wbase + (size_t)kc*64;
    }
#pragma unroll
    for (int o=0;o<64;o++) acc[o] = fmaf(a, wr[o], acc[o]);
  }
  // two-step LDS reduce (xor-swizzled, conflict-free), 32KB
  if (wid >= 2){
#pragma unroll
    for (int o=0;o<64;o++) red[(wid-2)*4096 + lane*64 + (o^lane)] = acc[o];
  }
  __syncthreads();
  if (wid < 2){
#pragma unroll
    for (int o=0;o<64;o++) red[wid*4096 + lane*64 + (o^lane)] += acc[o];
  }
  __syncthreads();
  const float bmy = sp_bias[threadIdx.x & 63];
#pragma unroll 4
  for (int i=0;i<16;i++){
    const int cell = threadIdx.x + 256*i;
    const int nn = cell>>6, o = cell&63;
    float s = red[nn*64 + (o^nn)] + red[4096 + nn*64 + (o^nn)];
    const size_t gi = (size_t)blockIdx.x*4096 + cell;
    if      (PASS==0) out_sp[gi] = s;
    else if (PASS==1) out_sp[gi] = out_sp[gi] + s;
    else              out_sp[gi] = eluf(out_sp[gi] + s + bmy);
  }
}

// ---------------------------------------------------------------- decoder: out_sp[NT,64] -> out[NT,2]
__global__ __launch_bounds__(256) void k_decoder(
    const float* __restrict__ out_sp,
    const float* __restrict__ dw0, const float* __restrict__ db0,
    const float* __restrict__ dw1, const float* __restrict__ db1,
    const float* __restrict__ dw2, const float* __restrict__ db2,
    float* __restrict__ out)
{
  int n = blockIdx.x*256 + threadIdx.x;
  bool ok = n < NT;
  int nn = ok ? n : 0;
  float h[64];
#pragma unroll
  for (int q=0;q<16;q++){
    float4 v = *(const float4*)&out_sp[(size_t)nn*64 + 4*q];
    h[4*q+0]=v.x; h[4*q+1]=v.y; h[4*q+2]=v.z; h[4*q+3]=v.w;
  }
  float g[32];
#pragma unroll
  for (int o=0;o<32;o++){
    float a = db0[o];
#pragma unroll
    for (int c=0;c<64;c++) a = fmaf(dw0[o*64+c], h[c], a);
    g[o] = eluf(a);
  }
  float q16[16];
#pragma unroll
  for (int o=0;o<16;o++){
    float a = db1[o];
#pragma unroll
    for (int c=0;c<32;c++) a = fmaf(dw1[o*32+c], g[c], a);
    q16[o] = eluf(a);
  }
  float o0 = db2[0], o1 = db2[1];
#pragma unroll
  for (int c=0;c<16;c++){
    o0 = fmaf(dw2[c],    q16[c], o0);
    o1 = fmaf(dw2[16+c], q16[c], o1);
  }
  if (ok){
    float2 r; r.x = tanhf(o0); r.y = tanhf(o1);
    *(float2*)&out[(size_t)n*2] = r;
  }
}

// ---------------------------------------------------------------- launcher
extern "C" void kernel_launch(void* const* d_in, const int* in_sizes, int n_in,
                              void* d_out, int out_size, void* d_ws, size_t ws_size,
                              hipStream_t stream)
{
  const float* x    = (const float*)d_in[1];
  const int*   ei   = (const int*)  d_in[2];
  const float* attr = (const float*)d_in[3];
  const float* ew0  = (const float*)d_in[4];  const float* eb0 = (const float*)d_in[5];
  const float* ew1  = (const float*)d_in[6];  const float* eb1 = (const float*)d_in[7];
  const float* ew2  = (const float*)d_in[8];  const float* eb2 = (const float*)d_in[9];
  const float* spw  = (const float*)d_in[10];
  const float* spr  = (const float*)d_in[11];
  const float* spb  = (const float*)d_in[12];
  const float* dw0  = (const float*)d_in[13]; const float* db0 = (const float*)d_in[14];
  const float* dw1  = (const float*)d_in[15]; const float* db1 = (const float*)d_in[16];
  const float* dw2  = (const float*)d_in[17]; const float* db2 = (const float*)d_in[18];
  float* out = (float*)d_out;

  char* p = (char*)d_ws;
  auto alloc = [&](size_t bytes)->char* {
    char* r = p; p += (bytes + 255) & ~size_t(255); return r;
  };
  float*  h_flat  = (float*) alloc((size_t)NT*64*4);     // 10.24 MB
  float*  h_flatT = (float*) alloc((size_t)NT*64*4);     // 10.24 MB
  float*  out_sp  = (float*) alloc((size_t)NT*64*4);     // 10.24 MB
  float*  accT    = (float*) alloc((size_t)576*NT*4);    // 92.16 MB
  float4* meta    = (float4*)alloc((size_t)EDG*16);      // 10.24 MB
  int*    rowptr  = (int*)   alloc((size_t)(NT+1)*4);
  int*    deg     = (int*)   alloc((size_t)NT*4);
  int*    cursor  = (int*)   alloc((size_t)NT*4);
  float*  deg_inv = (float*) alloc((size_t)NT*4);

  k_init   <<<(NT+255)/256,  256, 0, stream>>>(deg, cursor);
  k_encoder<<<(NT+255)/256,  256, 0, stream>>>(x, ew0,eb0, ew1,eb1, ew2,eb2, h_flat, h_flatT);
  k_count  <<<(EDG+255)/256, 256, 0, stream>>>(ei, deg);
  k_scan   <<<1, 1024, 0, stream>>>(deg, rowptr, deg_inv);
  k_fill   <<<(EDG+255)/256, 256, 0, stream>>>(ei, attr, rowptr, cursor, meta);

  k_gather<0,9>  <<<NT/16, 256, 0, stream>>>(meta, rowptr, deg_inv, h_flat, accT);
  k_gemm<0>      <<<NT/64, 256, 0, stream>>>(accT, h_flatT, spw, spr, spb, out_sp);
  k_gather<9,18> <<<NT/16, 256, 0, stream>>>(meta, rowptr, deg_inv, h_flat, accT);
  k_gemm<1>      <<<NT/64, 256, 0, stream>>>(accT, h_flatT, spw, spr, spb, out_sp);
  k_gather<18,27><<<NT/16, 256, 0, stream>>>(meta, rowptr, deg_inv, h_flat, accT);
  k_gemm<2>      <<<NT/64, 256, 0, stream>>>(accT, h_flatT, spw, spr, spb, out_sp);

  k_decoder<<<(NT+255)/256, 256, 0, stream>>>(out_sp, dw0,db0, dw1,db1, dw2,db2, out);
}

// Round 3
// 855.135 us; speedup vs baseline: 2.2266x; 2.2266x over previous
//
#include <hip/hip_runtime.h>
#include <math.h>

#define NT  40000   // total nodes (N*V)
#define EDG 640000  // edges

__device__ __forceinline__ float eluf(float v){ return v > 0.f ? v : expm1f(v); }

// ---------------------------------------------------------------- init: zero deg + cursor
__global__ void k_init(int* __restrict__ deg, int* __restrict__ cursor){
  int i = blockIdx.x*256 + threadIdx.x;
  if (i < NT){ deg[i] = 0; cursor[i] = 0; }
}

// ---------------------------------------------------------------- encoder: x[NT,2] -> h_flat[NT,64], h_flatT[64,NT]
__global__ __launch_bounds__(256) void k_encoder(
    const float* __restrict__ x,
    const float* __restrict__ w0, const float* __restrict__ b0,
    const float* __restrict__ w1, const float* __restrict__ b1,
    const float* __restrict__ w2, const float* __restrict__ b2,
    float* __restrict__ h_flat, float* __restrict__ h_flatT)
{
  int n = blockIdx.x*256 + threadIdx.x;
  bool ok = n < NT;
  int nn = ok ? n : 0;
  float x0 = x[(size_t)nn*2+0], x1 = x[(size_t)nn*2+1];
  float h1[16];
#pragma unroll
  for (int o=0;o<16;o++) h1[o] = eluf(b0[o] + w0[o*2+0]*x0 + w0[o*2+1]*x1);
  float h2[32];
#pragma unroll
  for (int o=0;o<32;o++){
    float a = b1[o];
#pragma unroll
    for (int c=0;c<16;c++) a = fmaf(w1[o*16+c], h1[c], a);
    h2[o] = eluf(a);
  }
#pragma unroll
  for (int o=0;o<64;o++){
    float a = b2[o];
#pragma unroll
    for (int c=0;c<32;c++) a = fmaf(w2[o*32+c], h2[c], a);
    float h = eluf(a);
    if (ok){ h_flat[(size_t)n*64+o] = h; h_flatT[(size_t)o*NT+n] = h; }
  }
}

// ---------------------------------------------------------------- degree count
__global__ void k_count(const int* __restrict__ ei, int* __restrict__ deg){
  int e = blockIdx.x*256 + threadIdx.x;
  if (e < EDG) atomicAdd(&deg[ei[EDG+e]], 1);
}

// ---------------------------------------------------------------- exclusive scan -> rowptr, deg_inv
__global__ __launch_bounds__(1024) void k_scan(
    const int* __restrict__ deg, int* __restrict__ rowptr, float* __restrict__ deg_inv)
{
  __shared__ int sums[1024];
  const int t = threadIdx.x;
  const int base = t*40;
  int s = 0;
  for (int i=0;i<40;i++){ int idx = base+i; if (idx < NT) s += deg[idx]; }
  sums[t] = s; __syncthreads();
  for (int off=1; off<1024; off<<=1){
    int v = (t >= off) ? sums[t-off] : 0;
    __syncthreads();
    sums[t] += v;
    __syncthreads();
  }
  int run = (t==0) ? 0 : sums[t-1];
  for (int i=0;i<40;i++){
    int idx = base+i;
    if (idx < NT){
      rowptr[idx] = run;
      int d = deg[idx];
      run += d;
      deg_inv[idx] = 1.0f / fmaxf((float)d, 1.0f);
    }
  }
  if (t == 1023) rowptr[NT] = run;
}

// ---------------------------------------------------------------- CSR fill: meta = {f0,f1,f2, src<<3|k0pack}
__global__ void k_fill(const int* __restrict__ ei, const float* __restrict__ attr,
                       const int* __restrict__ rowptr, int* __restrict__ cursor,
                       float4* __restrict__ meta)
{
  int e = blockIdx.x*256 + threadIdx.x;
  if (e >= EDG) return;
  int src = ei[e], dst = ei[EDG+e];
  float v0 = attr[(size_t)e*3+0]*2.f, v1 = attr[(size_t)e*3+1]*2.f, v2 = attr[(size_t)e*3+2]*2.f;
  float k00 = fminf(fmaxf(floorf(v0), 0.f), 1.f);
  float k01 = fminf(fmaxf(floorf(v1), 0.f), 1.f);
  float k02 = fminf(fmaxf(floorf(v2), 0.f), 1.f);
  int kp = ((int)k00)*4 + ((int)k01)*2 + (int)k02;
  float f0 = v0-k00, f1 = v1-k01, f2 = v2-k02;
  int pos = rowptr[dst] + atomicAdd(&cursor[dst], 1);
  meta[pos] = make_float4(f0, f1, f2, __int_as_float((src<<3) | kp));
}

// ---------------------------------------------------------------- gather: per-node reg acc, LDS meta staging (no spill)
// accT[(flat-KLO)*64 + c][node]
template<int KLO, int KHI>
__global__ __launch_bounds__(256) void k_gather(
    const float4* __restrict__ meta,
    const int* __restrict__ rowptr,
    const float* __restrict__ deg_inv,
    const float* __restrict__ h_flat,
    float* __restrict__ accT)
{
  constexpr int KCH = KHI - KLO;       // 9
  constexpr int J0  = KLO / 9;         // dim-0 slab index
  __shared__ float  stash[16*577];     // [node-in-block][576 rows + 1 pad] = 36.9 KB
  __shared__ float4 mstage[4][32];     // per-wave meta staging, 2 KB
  const int wid = threadIdx.x>>6, lane = threadIdx.x&63;
  float4* ms = mstage[wid];
  for (int s4=0; s4<4; s4++){
    const int nl = wid*4 + s4;
    const int n  = blockIdx.x*16 + nl;
    float acc[KCH];
#pragma unroll
    for (int k=0;k<KCH;k++) acc[k] = 0.f;
    const int beg = rowptr[n], end = rowptr[n+1];
    for (int jb = beg; jb < end; jb += 32){
      const int bn = min(32, end - jb);
      if (lane < bn) ms[lane] = meta[jb + lane];   // coalesced; broadcast-read below (intra-wave)
      __builtin_amdgcn_wave_barrier();
      for (int js = 0; js < bn; js += 16){
        const int cn = min(16, bn - js);
        float xb[16];
#pragma unroll
        for (int i=0;i<16;i++){
          xb[i] = 0.f;
          if (i < cn){
            const int pk  = __float_as_int(ms[js+i].w);
            const int k00 = (pk>>2)&1;
            if ((J0==1) || (k00 == (J0>>1)))        // J0-k00 in {0,1}
              xb[i] = h_flat[(size_t)(pk>>3)*64 + lane];
          }
        }
#pragma unroll
        for (int i=0;i<16;i++){
          if (i >= cn) break;
          const float4 m = ms[js+i];
          const int pk  = __float_as_int(m.w);
          const int k0p = pk & 7;
          const int k00 = (k0p>>2)&1;
          if (!((J0==1) || (k00 == (J0>>1)))) continue;
          const float xj = xb[i];
          const float f0 = m.x, f1 = m.y, f2 = m.z;
          const float u0 = 1.f-f0, u1 = 1.f-f1, u2 = 1.f-f2;
#define CORNER(K00,K01,K02,B0,B1,B2) { \
          constexpr int flat = (K00+B0)*9 + (K01+B1)*3 + (K02+B2); \
          if constexpr (flat >= KLO && flat < KHI) \
            acc[flat-KLO] = fmaf(((B0)?f0:u0)*((B1)?f1:u1)*((B2)?f2:u2), xj, acc[flat-KLO]); }
#define CASE8(K00,K01,K02) \
          CORNER(K00,K01,K02,0,0,0) CORNER(K00,K01,K02,0,0,1) \
          CORNER(K00,K01,K02,0,1,0) CORNER(K00,K01,K02,0,1,1) \
          CORNER(K00,K01,K02,1,0,0) CORNER(K00,K01,K02,1,0,1) \
          CORNER(K00,K01,K02,1,1,0) CORNER(K00,K01,K02,1,1,1)
          switch (k0p){
            case 0: CASE8(0,0,0) break;
            case 1: CASE8(0,0,1) break;
            case 2: CASE8(0,1,0) break;
            case 3: CASE8(0,1,1) break;
            case 4: CASE8(1,0,0) break;
            case 5: CASE8(1,0,1) break;
            case 6: CASE8(1,1,0) break;
            case 7: CASE8(1,1,1) break;
          }
#undef CORNER
#undef CASE8
        }
      }
    }
    const float dinv = deg_inv[n];
#pragma unroll
    for (int k=0;k<KCH;k++)
      stash[nl*577 + k*64 + lane] = acc[k]*dinv;   // stride-1 across lanes: conflict-free
  }
  __syncthreads();
  // flush: 576 rows x 16 nodes, coalesced float4 stores
  for (int idx = threadIdx.x; idx < 576*4; idx += 256){
    const int r = idx>>2, q = idx&3;
    float4 v;
    v.x = stash[(4*q+0)*577 + r];
    v.y = stash[(4*q+1)*577 + r];
    v.z = stash[(4*q+2)*577 + r];
    v.w = stash[(4*q+3)*577 + r];
    *(float4*)&accT[(size_t)r*NT + blockIdx.x*16 + 4*q] = v;
  }
}

// ---------------------------------------------------------------- contraction: 8x8 register tile per lane,
// wave = 64 nodes x 64 outputs, 4-way K split, LDS xor-swizzled reduce
template<int PASS>
__global__ __launch_bounds__(256) void k_gemm(
    const float* __restrict__ accT,      // [576][NT]
    const float* __restrict__ h_flatT,   // [64][NT]
    const float* __restrict__ sp_w,      // [27][64][64]
    const float* __restrict__ sp_root,   // [64][64]
    const float* __restrict__ sp_bias,   // [64]
    float* __restrict__ out_sp)          // [NT][64]
{
  __shared__ float red[2][64][64];       // 32 KB
  const int t = threadIdx.x, wid = t>>6, lane = t&63;
  const int ng = lane>>3, og = lane&7;
  const int n0 = blockIdx.x*64;          // grid 625 -> exact
  const size_t na = (size_t)n0 + ng*8;
  float acc[8][8];
#pragma unroll
  for (int i=0;i<8;i++)
#pragma unroll
    for (int j=0;j<8;j++) acc[i][j] = 0.f;
  const float* __restrict__ wb = sp_w + (size_t)PASS*576*64;
  const int k0 = wid*144;
#define GSTEP(APTR, WPTR, KC) { \
    const float4 alo = *(const float4*)&(APTR)[(size_t)(KC)*NT + na]; \
    const float4 ahi = *(const float4*)&(APTR)[(size_t)(KC)*NT + na + 4]; \
    const float4 wlo = *(const float4*)&(WPTR)[(size_t)(KC)*64 + og*8]; \
    const float4 whi = *(const float4*)&(WPTR)[(size_t)(KC)*64 + og*8 + 4]; \
    const float a[8] = {alo.x,alo.y,alo.z,alo.w,ahi.x,ahi.y,ahi.z,ahi.w}; \
    const float w[8] = {wlo.x,wlo.y,wlo.z,wlo.w,whi.x,whi.y,whi.z,whi.w}; \
    _Pragma("unroll") \
    for (int ii=0;ii<8;ii++){ \
      _Pragma("unroll") \
      for (int jj=0;jj<8;jj++) acc[ii][jj] = fmaf(a[ii], w[jj], acc[ii][jj]); } }
#pragma unroll 2
  for (int kc = k0; kc < k0+144; kc++) GSTEP(accT, wb, kc)
  if (PASS==2){
    const int r0 = wid*16;
#pragma unroll 2
    for (int kc = r0; kc < r0+16; kc++) GSTEP(h_flatT, sp_root, kc)
  }
#undef GSTEP
  // cross-wave reduce: waves 2,3 write; waves 0,1 add; all threads finalize.
  // col xor'd by ng -> per-instr 2-way bank aliasing only (free).
  if (wid >= 2){
#pragma unroll
    for (int i=0;i<8;i++)
#pragma unroll
      for (int j=0;j<8;j++)
        red[wid-2][ng*8+i][(og*8+j) ^ ng] = acc[i][j];
  }
  __syncthreads();
  if (wid < 2){
#pragma unroll
    for (int i=0;i<8;i++)
#pragma unroll
      for (int j=0;j<8;j++)
        red[wid][ng*8+i][(og*8+j) ^ ng] += acc[i][j];
  }
  __syncthreads();
#pragma unroll 4
  for (int it=0; it<16; it++){
    const int cell = it*256 + t;
    const int nn = cell>>6, o = cell&63;
    const int xr = nn>>3;
    const float s = red[0][nn][o ^ xr] + red[1][nn][o ^ xr];
    const size_t gi = (size_t)n0*64 + cell;
    if      (PASS==0) out_sp[gi] = s;
    else if (PASS==1) out_sp[gi] += s;
    else              out_sp[gi] = eluf(out_sp[gi] + s + sp_bias[o]);
  }
}

// ---------------------------------------------------------------- decoder: out_sp[NT,64] -> out[NT,2]
__global__ __launch_bounds__(256) void k_decoder(
    const float* __restrict__ out_sp,
    const float* __restrict__ dw0, const float* __restrict__ db0,
    const float* __restrict__ dw1, const float* __restrict__ db1,
    const float* __restrict__ dw2, const float* __restrict__ db2,
    float* __restrict__ out)
{
  int n = blockIdx.x*256 + threadIdx.x;
  bool ok = n < NT;
  int nn = ok ? n : 0;
  float h[64];
#pragma unroll
  for (int q=0;q<16;q++){
    float4 v = *(const float4*)&out_sp[(size_t)nn*64 + 4*q];
    h[4*q+0]=v.x; h[4*q+1]=v.y; h[4*q+2]=v.z; h[4*q+3]=v.w;
  }
  float g[32];
#pragma unroll
  for (int o=0;o<32;o++){
    float a = db0[o];
#pragma unroll
    for (int c=0;c<64;c++) a = fmaf(dw0[o*64+c], h[c], a);
    g[o] = eluf(a);
  }
  float q16[16];
#pragma unroll
  for (int o=0;o<16;o++){
    float a = db1[o];
#pragma unroll
    for (int c=0;c<32;c++) a = fmaf(dw1[o*32+c], g[c], a);
    q16[o] = eluf(a);
  }
  float o0 = db2[0], o1 = db2[1];
#pragma unroll
  for (int c=0;c<16;c++){
    o0 = fmaf(dw2[c],    q16[c], o0);
    o1 = fmaf(dw2[16+c], q16[c], o1);
  }
  if (ok){
    float2 r; r.x = tanhf(o0); r.y = tanhf(o1);
    *(float2*)&out[(size_t)n*2] = r;
  }
}

// ---------------------------------------------------------------- launcher
extern "C" void kernel_launch(void* const* d_in, const int* in_sizes, int n_in,
                              void* d_out, int out_size, void* d_ws, size_t ws_size,
                              hipStream_t stream)
{
  const float* x    = (const float*)d_in[1];
  const int*   ei   = (const int*)  d_in[2];
  const float* attr = (const float*)d_in[3];
  const float* ew0  = (const float*)d_in[4];  const float* eb0 = (const float*)d_in[5];
  const float* ew1  = (const float*)d_in[6];  const float* eb1 = (const float*)d_in[7];
  const float* ew2  = (const float*)d_in[8];  const float* eb2 = (const float*)d_in[9];
  const float* spw  = (const float*)d_in[10];
  const float* spr  = (const float*)d_in[11];
  const float* spb  = (const float*)d_in[12];
  const float* dw0  = (const float*)d_in[13]; const float* db0 = (const float*)d_in[14];
  const float* dw1  = (const float*)d_in[15]; const float* db1 = (const float*)d_in[16];
  const float* dw2  = (const float*)d_in[17]; const float* db2 = (const float*)d_in[18];
  float* out = (float*)d_out;

  char* p = (char*)d_ws;
  auto alloc = [&](size_t bytes)->char* {
    char* r = p; p += (bytes + 255) & ~size_t(255); return r;
  };
  float*  h_flat  = (float*) alloc((size_t)NT*64*4);     // 10.24 MB
  float*  h_flatT = (float*) alloc((size_t)NT*64*4);     // 10.24 MB
  float*  out_sp  = (float*) alloc((size_t)NT*64*4);     // 10.24 MB
  float*  accT    = (float*) alloc((size_t)576*NT*4);    // 92.16 MB
  float4* meta    = (float4*)alloc((size_t)EDG*16);      // 10.24 MB
  int*    rowptr  = (int*)   alloc((size_t)(NT+1)*4);
  int*    deg     = (int*)   alloc((size_t)NT*4);
  int*    cursor  = (int*)   alloc((size_t)NT*4);
  float*  deg_inv = (float*) alloc((size_t)NT*4);

  k_init   <<<(NT+255)/256,  256, 0, stream>>>(deg, cursor);
  k_encoder<<<(NT+255)/256,  256, 0, stream>>>(x, ew0,eb0, ew1,eb1, ew2,eb2, h_flat, h_flatT);
  k_count  <<<(EDG+255)/256, 256, 0, stream>>>(ei, deg);
  k_scan   <<<1, 1024, 0, stream>>>(deg, rowptr, deg_inv);
  k_fill   <<<(EDG+255)/256, 256, 0, stream>>>(ei, attr, rowptr, cursor, meta);

  k_gather<0,9>  <<<NT/16, 256, 0, stream>>>(meta, rowptr, deg_inv, h_flat, accT);
  k_gemm<0>      <<<NT/64, 256, 0, stream>>>(accT, h_flatT, spw, spr, spb, out_sp);
  k_gather<9,18> <<<NT/16, 256, 0, stream>>>(meta, rowptr, deg_inv, h_flat, accT);
  k_gemm<1>      <<<NT/64, 256, 0, stream>>>(accT, h_flatT, spw, spr, spb, out_sp);
  k_gather<18,27><<<NT/16, 256, 0, stream>>>(meta, rowptr, deg_inv, h_flat, accT);
  k_gemm<2>      <<<NT/64, 256, 0, stream>>>(accT, h_flatT, spw, spr, spb, out_sp);

  k_decoder<<<(NT+255)/256, 256, 0, stream>>>(out_sp, dw0,db0, dw1,db1, dw2,db2, out);
}

// Round 5
// 700.150 us; speedup vs baseline: 2.7195x; 1.2214x over previous
//
#include <hip/hip_runtime.h>
#include <hip/hip_fp16.h>
#include <math.h>

#define NT  40000   // total nodes (N*V)
#define EDG 640000  // edges

__device__ __forceinline__ float eluf(float v){ return v > 0.f ? v : expm1f(v); }
__device__ __forceinline__ unsigned pack2h(float a, float b){
  return __builtin_bit_cast(unsigned, __floats2half2_rn(a, b));
}

// ---------------------------------------------------------------- init: zero deg + cursor
__global__ void k_init(int* __restrict__ deg, int* __restrict__ cursor){
  int i = blockIdx.x*256 + threadIdx.x;
  if (i < NT){ deg[i] = 0; cursor[i] = 0; }
}

// ---------------------------------------------------------------- encoder: x[NT,2] -> h_flat[NT,64] (f32), hT[64,NT] (f16)
__global__ __launch_bounds__(256) void k_encoder(
    const float* __restrict__ x,
    const float* __restrict__ w0, const float* __restrict__ b0,
    const float* __restrict__ w1, const float* __restrict__ b1,
    const float* __restrict__ w2, const float* __restrict__ b2,
    float* __restrict__ h_flat, __half* __restrict__ hT)
{
  int n = blockIdx.x*256 + threadIdx.x;
  bool ok = n < NT;
  int nn = ok ? n : 0;
  float x0 = x[(size_t)nn*2+0], x1 = x[(size_t)nn*2+1];
  float h1[16];
#pragma unroll
  for (int o=0;o<16;o++) h1[o] = eluf(b0[o] + w0[o*2+0]*x0 + w0[o*2+1]*x1);
  float h2[32];
#pragma unroll
  for (int o=0;o<32;o++){
    float a = b1[o];
#pragma unroll
    for (int c=0;c<16;c++) a = fmaf(w1[o*16+c], h1[c], a);
    h2[o] = eluf(a);
  }
#pragma unroll
  for (int o=0;o<64;o++){
    float a = b2[o];
#pragma unroll
    for (int c=0;c<32;c++) a = fmaf(w2[o*32+c], h2[c], a);
    float h = eluf(a);
    if (ok){ h_flat[(size_t)n*64+o] = h; hT[(size_t)o*NT+n] = __float2half_rn(h); }
  }
}

// ---------------------------------------------------------------- degree count
__global__ void k_count(const int* __restrict__ ei, int* __restrict__ deg){
  int e = blockIdx.x*256 + threadIdx.x;
  if (e < EDG) atomicAdd(&deg[ei[EDG+e]], 1);
}

// ---------------------------------------------------------------- exclusive scan -> rowptr, deg_inv
__global__ __launch_bounds__(1024) void k_scan(
    const int* __restrict__ deg, int* __restrict__ rowptr, float* __restrict__ deg_inv)
{
  __shared__ int sums[1024];
  const int t = threadIdx.x;
  const int base = t*40;
  int s = 0;
  for (int i=0;i<40;i++){ int idx = base+i; if (idx < NT) s += deg[idx]; }
  sums[t] = s; __syncthreads();
  for (int off=1; off<1024; off<<=1){
    int v = (t >= off) ? sums[t-off] : 0;
    __syncthreads();
    sums[t] += v;
    __syncthreads();
  }
  int run = (t==0) ? 0 : sums[t-1];
  for (int i=0;i<40;i++){
    int idx = base+i;
    if (idx < NT){
      rowptr[idx] = run;
      int d = deg[idx];
      run += d;
      deg_inv[idx] = 1.0f / fmaxf((float)d, 1.0f);
    }
  }
  if (t == 1023) rowptr[NT] = run;
}

// ---------------------------------------------------------------- CSR fill: meta = {f0,f1,f2,-}, pkarr = src<<3|k0pack
__global__ void k_fill(const int* __restrict__ ei, const float* __restrict__ attr,
                       const int* __restrict__ rowptr, int* __restrict__ cursor,
                       float4* __restrict__ meta, int* __restrict__ pkarr)
{
  int e = blockIdx.x*256 + threadIdx.x;
  if (e >= EDG) return;
  int src = ei[e], dst = ei[EDG+e];
  float v0 = attr[(size_t)e*3+0]*2.f, v1 = attr[(size_t)e*3+1]*2.f, v2 = attr[(size_t)e*3+2]*2.f;
  float k00 = fminf(fmaxf(floorf(v0), 0.f), 1.f);
  float k01 = fminf(fmaxf(floorf(v1), 0.f), 1.f);
  float k02 = fminf(fmaxf(floorf(v2), 0.f), 1.f);
  int kp = ((int)k00)*4 + ((int)k01)*2 + (int)k02;
  float f0 = v0-k00, f1 = v1-k01, f2 = v2-k02;
  int pos = rowptr[dst] + atomicAdd(&cursor[dst], 1);
  meta[pos]  = make_float4(f0, f1, f2, 0.f);
  pkarr[pos] = (src<<3) | kp;
}

// ---------------------------------------------------------------- single-pass gather: acc[27] per node, scalar meta path
// Per edge: pk (src,k0) goes through SGPRs (readlane); weights stay vector.
__device__ __forceinline__ void gather_node(
    int n, int lane, float4* __restrict__ ms,
    const float4* __restrict__ meta, const int* __restrict__ pkarr,
    const int* __restrict__ rowptr, const float* __restrict__ h_flat,
    float (&acc)[27])
{
#pragma unroll
  for (int k=0;k<27;k++) acc[k] = 0.f;
  const int beg = rowptr[n], end = rowptr[n+1];
  if (beg == end) return;
  const int endm1 = end - 1;
  for (int jb = beg; jb < end; jb += 8){
    const int cn = min(8, end - jb);
    if (lane < 8) ms[lane] = meta[min(jb + lane, endm1)];
    __builtin_amdgcn_wave_barrier();
    const int pkv = pkarr[min(jb + lane, endm1)];
    int pks[8];
#pragma unroll
    for (int i=0;i<8;i++) pks[i] = __builtin_amdgcn_readlane(pkv, i);
    float xb[8];
#pragma unroll
    for (int i=0;i<8;i++) xb[i] = h_flat[(size_t)(pks[i]>>3)*64 + lane];
#pragma unroll
    for (int i=0;i<8;i++){
      if (i >= cn) break;
      const float4 m = ms[i];
      const float xj = xb[i];
      const float u0 = 1.f-m.x, u1 = 1.f-m.y, u2 = 1.f-m.z;
      const float t0 = u0*xj,  t1 = m.x*xj;
      const float p00 = u1*u2, p01 = u1*m.z, p10 = m.y*u2, p11 = m.y*m.z;
#define DO_CASE(B) \
      acc[(B)+0]  = fmaf(p00,t0,acc[(B)+0]);  \
      acc[(B)+1]  = fmaf(p01,t0,acc[(B)+1]);  \
      acc[(B)+3]  = fmaf(p10,t0,acc[(B)+3]);  \
      acc[(B)+4]  = fmaf(p11,t0,acc[(B)+4]);  \
      acc[(B)+9]  = fmaf(p00,t1,acc[(B)+9]);  \
      acc[(B)+10] = fmaf(p01,t1,acc[(B)+10]); \
      acc[(B)+12] = fmaf(p10,t1,acc[(B)+12]); \
      acc[(B)+13] = fmaf(p11,t1,acc[(B)+13]);
      switch (pks[i] & 7){   // scalar (SGPR) switch: k0p -> base = k00*9+k01*3+k02
        case 0: { DO_CASE(0)  } break;
        case 1: { DO_CASE(1)  } break;
        case 2: { DO_CASE(3)  } break;
        case 3: { DO_CASE(4)  } break;
        case 4: { DO_CASE(9)  } break;
        case 5: { DO_CASE(10) } break;
        case 6: { DO_CASE(12) } break;
        case 7: { DO_CASE(13) } break;
      }
#undef DO_CASE
    }
  }
}

__global__ __launch_bounds__(256) void k_gather(
    const float4* __restrict__ meta,
    const int* __restrict__ pkarr,
    const int* __restrict__ rowptr,
    const float* __restrict__ deg_inv,
    const float* __restrict__ h_flat,
    __half* __restrict__ accT)            // [1728][NT] f16
{
  __shared__ float  stash[8*577];         // [node-in-block][576 rows + pad] = 18.5 KB
  __shared__ float4 mstage[4][8];
  const int wid = threadIdx.x>>6, lane = threadIdx.x&63;
  float4* ms = mstage[wid];
  const int nA = blockIdx.x*8 + wid*2, nB = nA + 1;
  float accA[27], accB[27];
  gather_node(nA, lane, ms, meta, pkarr, rowptr, h_flat, accA);
  gather_node(nB, lane, ms, meta, pkarr, rowptr, h_flat, accB);
  const float dA = deg_inv[nA], dB = deg_inv[nB];
  const int nlA = wid*2, nlB = nlA + 1;
#pragma unroll
  for (int c=0;c<3;c++){
#pragma unroll
    for (int kl=0; kl<9; kl++){
      stash[nlA*577 + kl*64 + lane] = accA[c*9+kl]*dA;
      stash[nlB*577 + kl*64 + lane] = accB[c*9+kl]*dB;
    }
    __syncthreads();
    for (int r = threadIdx.x; r < 576; r += 256){
      const int R = c*576 + r;             // global row = k*64 + cin
      uint4 u;
      u.x = pack2h(stash[0*577+r], stash[1*577+r]);
      u.y = pack2h(stash[2*577+r], stash[3*577+r]);
      u.z = pack2h(stash[4*577+r], stash[5*577+r]);
      u.w = pack2h(stash[6*577+r], stash[7*577+r]);
      *(uint4*)&accT[(size_t)R*NT + blockIdx.x*8] = u;   // 16B coalesced per row
    }
    __syncthreads();
  }
}

// ---------------------------------------------------------------- contraction: K=1792 (1728 spline + 64 root), fp16 A, fp32 W
// 8x8 register tile per lane; wave = 64 nodes x 64 outputs; 4-way K split; LDS xor-swizzled reduce
__global__ __launch_bounds__(256) void k_gemm(
    const __half* __restrict__ accT,     // [1728][NT]
    const __half* __restrict__ hT,       // [64][NT]
    const float* __restrict__ sp_w,      // [1728][64]
    const float* __restrict__ sp_root,   // [64][64]
    const float* __restrict__ sp_bias,   // [64]
    float* __restrict__ out_sp)          // [NT][64]
{
  __shared__ float red[2][64][64];       // 32 KB
  const int t = threadIdx.x, wid = t>>6, lane = t&63;
  const int ng = lane>>3, og = lane&7;
  const int n0 = blockIdx.x*64;          // grid 625 -> exact
  const size_t na = (size_t)n0 + ng*8;
  float acc[8][8];
#pragma unroll
  for (int i=0;i<8;i++)
#pragma unroll
    for (int j=0;j<8;j++) acc[i][j] = 0.f;
  const int k0 = wid*448;
#pragma unroll 2
  for (int kc = k0; kc < k0+448; kc++){
    const __half* ar; const float* wr;
    if (kc < 1728){ ar = accT + (size_t)kc*NT;        wr = sp_w    + (size_t)kc*64; }
    else          { ar = hT   + (size_t)(kc-1728)*NT; wr = sp_root + (size_t)(kc-1728)*64; }
    const uint4  av  = *(const uint4*)(ar + na);
    const float4 wlo = *(const float4*)(wr + og*8);
    const float4 whi = *(const float4*)(wr + og*8 + 4);
    const float2 a01 = __half22float2(__builtin_bit_cast(__half2, av.x));
    const float2 a23 = __half22float2(__builtin_bit_cast(__half2, av.y));
    const float2 a45 = __half22float2(__builtin_bit_cast(__half2, av.z));
    const float2 a67 = __half22float2(__builtin_bit_cast(__half2, av.w));
    const float a[8] = {a01.x,a01.y,a23.x,a23.y,a45.x,a45.y,a67.x,a67.y};
    const float w[8] = {wlo.x,wlo.y,wlo.z,wlo.w,whi.x,whi.y,whi.z,whi.w};
#pragma unroll
    for (int ii=0;ii<8;ii++)
#pragma unroll
      for (int jj=0;jj<8;jj++) acc[ii][jj] = fmaf(a[ii], w[jj], acc[ii][jj]);
  }
  // cross-wave reduce: waves 2,3 write; waves 0,1 add; all threads finalize.
  if (wid >= 2){
#pragma unroll
    for (int i=0;i<8;i++)
#pragma unroll
      for (int j=0;j<8;j++)
        red[wid-2][ng*8+i][(og*8+j) ^ ng] = acc[i][j];
  }
  __syncthreads();
  if (wid < 2){
#pragma unroll
    for (int i=0;i<8;i++)
#pragma unroll
      for (int j=0;j<8;j++)
        red[wid][ng*8+i][(og*8+j) ^ ng] += acc[i][j];
  }
  __syncthreads();
#pragma unroll 4
  for (int it=0; it<16; it++){
    const int cell = it*256 + t;
    const int nn = cell>>6, o = cell&63;
    const int xr = nn>>3;
    const float s = red[0][nn][o ^ xr] + red[1][nn][o ^ xr];
    out_sp[(size_t)n0*64 + cell] = eluf(s + sp_bias[o]);
  }
}

// ---------------------------------------------------------------- decoder: out_sp[NT,64] -> out[NT,2]
__global__ __launch_bounds__(256) void k_decoder(
    const float* __restrict__ out_sp,
    const float* __restrict__ dw0, const float* __restrict__ db0,
    const float* __restrict__ dw1, const float* __restrict__ db1,
    const float* __restrict__ dw2, const float* __restrict__ db2,
    float* __restrict__ out)
{
  int n = blockIdx.x*256 + threadIdx.x;
  bool ok = n < NT;
  int nn = ok ? n : 0;
  float h[64];
#pragma unroll
  for (int q=0;q<16;q++){
    float4 v = *(const float4*)&out_sp[(size_t)nn*64 + 4*q];
    h[4*q+0]=v.x; h[4*q+1]=v.y; h[4*q+2]=v.z; h[4*q+3]=v.w;
  }
  float g[32];
#pragma unroll
  for (int o=0;o<32;o++){
    float a = db0[o];
#pragma unroll
    for (int c=0;c<64;c++) a = fmaf(dw0[o*64+c], h[c], a);
    g[o] = eluf(a);
  }
  float q16[16];
#pragma unroll
  for (int o=0;o<16;o++){
    float a = db1[o];
#pragma unroll
    for (int c=0;c<32;c++) a = fmaf(dw1[o*32+c], g[c], a);
    q16[o] = eluf(a);
  }
  float o0 = db2[0], o1 = db2[1];
#pragma unroll
  for (int c=0;c<16;c++){
    o0 = fmaf(dw2[c],    q16[c], o0);
    o1 = fmaf(dw2[16+c], q16[c], o1);
  }
  if (ok){
    float2 r; r.x = tanhf(o0); r.y = tanhf(o1);
    *(float2*)&out[(size_t)n*2] = r;
  }
}

// ---------------------------------------------------------------- launcher
extern "C" void kernel_launch(void* const* d_in, const int* in_sizes, int n_in,
                              void* d_out, int out_size, void* d_ws, size_t ws_size,
                              hipStream_t stream)
{
  const float* x    = (const float*)d_in[1];
  const int*   ei   = (const int*)  d_in[2];
  const float* attr = (const float*)d_in[3];
  const float* ew0  = (const float*)d_in[4];  const float* eb0 = (const float*)d_in[5];
  const float* ew1  = (const float*)d_in[6];  const float* eb1 = (const float*)d_in[7];
  const float* ew2  = (const float*)d_in[8];  const float* eb2 = (const float*)d_in[9];
  const float* spw  = (const float*)d_in[10];
  const float* spr  = (const float*)d_in[11];
  const float* spb  = (const float*)d_in[12];
  const float* dw0  = (const float*)d_in[13]; const float* db0 = (const float*)d_in[14];
  const float* dw1  = (const float*)d_in[15]; const float* db1 = (const float*)d_in[16];
  const float* dw2  = (const float*)d_in[17]; const float* db2 = (const float*)d_in[18];
  float* out = (float*)d_out;

  char* p = (char*)d_ws;
  auto alloc = [&](size_t bytes)->char* {
    char* r = p; p += (bytes + 255) & ~size_t(255); return r;
  };
  float*  h_flat  = (float*) alloc((size_t)NT*64*4);      // 10.24 MB
  __half* hT      = (__half*)alloc((size_t)64*NT*2);      //  5.12 MB
  float*  out_sp  = (float*) alloc((size_t)NT*64*4);      // 10.24 MB
  __half* accT    = (__half*)alloc((size_t)1728*NT*2);    // 138.24 MB
  float4* meta    = (float4*)alloc((size_t)EDG*16);       // 10.24 MB
  int*    pkarr   = (int*)   alloc((size_t)EDG*4);        //  2.56 MB
  int*    rowptr  = (int*)   alloc((size_t)(NT+1)*4);
  int*    deg     = (int*)   alloc((size_t)NT*4);
  int*    cursor  = (int*)   alloc((size_t)NT*4);
  float*  deg_inv = (float*) alloc((size_t)NT*4);

  k_init   <<<(NT+255)/256,  256, 0, stream>>>(deg, cursor);
  k_encoder<<<(NT+255)/256,  256, 0, stream>>>(x, ew0,eb0, ew1,eb1, ew2,eb2, h_flat, hT);
  k_count  <<<(EDG+255)/256, 256, 0, stream>>>(ei, deg);
  k_scan   <<<1, 1024, 0, stream>>>(deg, rowptr, deg_inv);
  k_fill   <<<(EDG+255)/256, 256, 0, stream>>>(ei, attr, rowptr, cursor, meta, pkarr);
  k_gather <<<NT/8,  256, 0, stream>>>(meta, pkarr, rowptr, deg_inv, h_flat, accT);
  k_gemm   <<<NT/64, 256, 0, stream>>>(accT, hT, spw, spr, spb, out_sp);
  k_decoder<<<(NT+255)/256, 256, 0, stream>>>(out_sp, dw0,db0, dw1,db1, dw2,db2, out);
}

// Round 8
// 522.991 us; speedup vs baseline: 3.6407x; 1.3387x over previous
//
#include <hip/hip_runtime.h>
#include <hip/hip_fp16.h>
#include <math.h>

#define NT  40000   // total nodes (N*V)
#define EDG 640000  // edges
#define KTOT 1792   // 1728 spline + 64 root
#define NCH  56     // K chunks of 32

typedef _Float16 half8 __attribute__((ext_vector_type(8)));
typedef float    f32x4 __attribute__((ext_vector_type(4)));

__device__ __forceinline__ float eluf(float v){ return v > 0.f ? v : expm1f(v); }

// ---------------------------------------------------------------- init: zero deg + cursor
__global__ void k_init(int* __restrict__ deg, int* __restrict__ cursor){
  int i = blockIdx.x*256 + threadIdx.x;
  if (i < NT){ deg[i] = 0; cursor[i] = 0; }
}

// ---------------------------------------------------------------- encoder: x[NT,2] -> h_flat[NT,64] f32, accN[n][1728+c] f16 (root cols)
__global__ __launch_bounds__(256) void k_encoder(
    const float* __restrict__ x,
    const float* __restrict__ w0, const float* __restrict__ b0,
    const float* __restrict__ w1, const float* __restrict__ b1,
    const float* __restrict__ w2, const float* __restrict__ b2,
    float* __restrict__ h_flat, _Float16* __restrict__ accN)
{
  int n = blockIdx.x*256 + threadIdx.x;
  bool ok = n < NT;
  int nn = ok ? n : 0;
  float x0 = x[(size_t)nn*2+0], x1 = x[(size_t)nn*2+1];
  float h1[16];
#pragma unroll
  for (int o=0;o<16;o++) h1[o] = eluf(b0[o] + w0[o*2+0]*x0 + w0[o*2+1]*x1);
  float h2[32];
#pragma unroll
  for (int o=0;o<32;o++){
    float a = b1[o];
#pragma unroll
    for (int c=0;c<16;c++) a = fmaf(w1[o*16+c], h1[c], a);
    h2[o] = eluf(a);
  }
#pragma unroll
  for (int o=0;o<64;o++){
    float a = b2[o];
#pragma unroll
    for (int c=0;c<32;c++) a = fmaf(w2[o*32+c], h2[c], a);
    float h = eluf(a);
    if (ok){
      h_flat[(size_t)n*64+o] = h;
      accN[(size_t)n*KTOT + 1728 + o] = (_Float16)h;
    }
  }
}

// ---------------------------------------------------------------- degree count
__global__ void k_count(const int* __restrict__ ei, int* __restrict__ deg){
  int e = blockIdx.x*256 + threadIdx.x;
  if (e < EDG) atomicAdd(&deg[ei[EDG+e]], 1);
}

// ---------------------------------------------------------------- parallel scan (3 kernels, 40 blocks of 1024)
__global__ void k_scanA(const int* __restrict__ deg, int* __restrict__ bsum){
  __shared__ int sm[256];
  const int t = threadIdx.x, b = blockIdx.x;
  const int base = b*1024 + t*4;
  int s = 0;
#pragma unroll
  for (int i=0;i<4;i++){ int idx = base+i; if (idx < NT) s += deg[idx]; }
  sm[t] = s; __syncthreads();
  for (int off=128; off>0; off>>=1){ if (t < off) sm[t] += sm[t+off]; __syncthreads(); }
  if (t == 0) bsum[b] = sm[0];
}
__global__ void k_scanB(const int* __restrict__ bsum, int* __restrict__ boffs,
                        int* __restrict__ rowptr){
  if (threadIdx.x == 0){
    int run = 0;
    for (int i=0;i<40;i++){ boffs[i] = run; run += bsum[i]; }
    rowptr[NT] = run;
  }
}
__global__ void k_scanC(const int* __restrict__ deg, const int* __restrict__ boffs,
                        int* __restrict__ rowptr, float* __restrict__ deg_inv){
  __shared__ int sm[256];
  const int t = threadIdx.x, b = blockIdx.x;
  const int base = b*1024 + t*4;
  int v[4]; int s = 0;
#pragma unroll
  for (int i=0;i<4;i++){ int idx = base+i; v[i] = (idx < NT) ? deg[idx] : 0; s += v[i]; }
  sm[t] = s; __syncthreads();
  for (int off=1; off<256; off<<=1){
    int u = (t >= off) ? sm[t-off] : 0;
    __syncthreads();
    sm[t] += u;
    __syncthreads();
  }
  int excl = sm[t] - s + boffs[b];
#pragma unroll
  for (int i=0;i<4;i++){
    int idx = base+i;
    if (idx < NT){
      rowptr[idx] = excl;
      deg_inv[idx] = 1.0f / fmaxf((float)v[i], 1.0f);
      excl += v[i];
    }
  }
}

// ---------------------------------------------------------------- CSR fill: meta = {f0,f1,f2,-}, pkarr = src<<3|k0pack
__global__ void k_fill(const int* __restrict__ ei, const float* __restrict__ attr,
                       const int* __restrict__ rowptr, int* __restrict__ cursor,
                       float4* __restrict__ meta, int* __restrict__ pkarr)
{
  int e = blockIdx.x*256 + threadIdx.x;
  if (e >= EDG) return;
  int src = ei[e], dst = ei[EDG+e];
  float v0 = attr[(size_t)e*3+0]*2.f, v1 = attr[(size_t)e*3+1]*2.f, v2 = attr[(size_t)e*3+2]*2.f;
  float k00 = fminf(fmaxf(floorf(v0), 0.f), 1.f);
  float k01 = fminf(fmaxf(floorf(v1), 0.f), 1.f);
  float k02 = fminf(fmaxf(floorf(v2), 0.f), 1.f);
  int kp = ((int)k00)*4 + ((int)k01)*2 + (int)k02;
  float f0 = v0-k00, f1 = v1-k01, f2 = v2-k02;
  int pos = rowptr[dst] + atomicAdd(&cursor[dst], 1);
  meta[pos]  = make_float4(f0, f1, f2, 0.f);
  pkarr[pos] = (src<<3) | kp;
}

// ---------------------------------------------------------------- W pre-swizzle into MFMA B-frag order (fp16)
// wswz[(chunk*4+tile)*64 + lane] = half8{ W[chunk*32 + (lane>>4)*8 + j][tile*16 + (lane&15)] }
__global__ __launch_bounds__(256) void k_prep(
    const float* __restrict__ sp_w,      // [1728][64]
    const float* __restrict__ sp_root,   // [64][64]
    half8* __restrict__ wswz)
{
  const int t = threadIdx.x, c = blockIdx.x;      // grid 56
  const int tile = t>>6, lane = t&63;
  const int kb = lane>>4, col = tile*16 + (lane&15);
  half8 h;
#pragma unroll
  for (int j=0;j<8;j++){
    const int k = c*32 + kb*8 + j;
    const float v = (k < 1728) ? sp_w[(size_t)k*64 + col] : sp_root[(size_t)(k-1728)*64 + col];
    h[j] = (_Float16)v;
  }
  wswz[(c*4 + tile)*64 + lane] = h;
}

// ---------------------------------------------------------------- single-pass gather: acc[27] per node, scalar meta path
__device__ __forceinline__ void gather_node(
    int n, int lane, float4* __restrict__ ms,
    const float4* __restrict__ meta, const int* __restrict__ pkarr,
    const int* __restrict__ rowptr, const float* __restrict__ h_flat,
    float (&acc)[27])
{
#pragma unroll
  for (int k=0;k<27;k++) acc[k] = 0.f;
  const int beg = rowptr[n], end = rowptr[n+1];
  if (beg == end) return;
  const int endm1 = end - 1;
  for (int jb = beg; jb < end; jb += 8){
    const int cn = min(8, end - jb);
    if (lane < 8) ms[lane] = meta[min(jb + lane, endm1)];
    __builtin_amdgcn_wave_barrier();
    const int pkv = pkarr[min(jb + lane, endm1)];
    int pks[8];
#pragma unroll
    for (int i=0;i<8;i++) pks[i] = __builtin_amdgcn_readlane(pkv, i);
    float xb[8];
#pragma unroll
    for (int i=0;i<8;i++) xb[i] = h_flat[(size_t)(pks[i]>>3)*64 + lane];
#pragma unroll
    for (int i=0;i<8;i++){
      if (i >= cn) break;
      const float4 m = ms[i];
      const float xj = xb[i];
      const float u0 = 1.f-m.x, u1 = 1.f-m.y, u2 = 1.f-m.z;
      const float t0 = u0*xj,  t1 = m.x*xj;
      const float p00 = u1*u2, p01 = u1*m.z, p10 = m.y*u2, p11 = m.y*m.z;
#define DO_CASE(B) \
      acc[(B)+0]  = fmaf(p00,t0,acc[(B)+0]);  \
      acc[(B)+1]  = fmaf(p01,t0,acc[(B)+1]);  \
      acc[(B)+3]  = fmaf(p10,t0,acc[(B)+3]);  \
      acc[(B)+4]  = fmaf(p11,t0,acc[(B)+4]);  \
      acc[(B)+9]  = fmaf(p00,t1,acc[(B)+9]);  \
      acc[(B)+10] = fmaf(p01,t1,acc[(B)+10]); \
      acc[(B)+12] = fmaf(p10,t1,acc[(B)+12]); \
      acc[(B)+13] = fmaf(p11,t1,acc[(B)+13]);
      switch (pks[i] & 7){   // scalar switch: k0p -> base = k00*9+k01*3+k02
        case 0: { DO_CASE(0)  } break;
        case 1: { DO_CASE(1)  } break;
        case 2: { DO_CASE(3)  } break;
        case 3: { DO_CASE(4)  } break;
        case 4: { DO_CASE(9)  } break;
        case 5: { DO_CASE(10) } break;
        case 6: { DO_CASE(12) } break;
        case 7: { DO_CASE(13) } break;
      }
#undef DO_CASE
    }
  }
}

__global__ __launch_bounds__(256) void k_gather(
    const float4* __restrict__ meta,
    const int* __restrict__ pkarr,
    const int* __restrict__ rowptr,
    const float* __restrict__ deg_inv,
    const float* __restrict__ h_flat,
    _Float16* __restrict__ accN)          // [NT][1792], cols 0..1727
{
  __shared__ float4 mstage[4][8];
  const int wid = threadIdx.x>>6, lane = threadIdx.x&63;
  float4* ms = mstage[wid];
  const int nA = blockIdx.x*8 + wid*2, nB = nA + 1;
  float accA[27], accB[27];
  gather_node(nA, lane, ms, meta, pkarr, rowptr, h_flat, accA);
  gather_node(nB, lane, ms, meta, pkarr, rowptr, h_flat, accB);
  const float dA = deg_inv[nA], dB = deg_inv[nB];
#pragma unroll
  for (int k=0;k<27;k++)
    accN[(size_t)nA*KTOT + k*64 + lane] = (_Float16)(accA[k]*dA);
#pragma unroll
  for (int k=0;k<27;k++)
    accN[(size_t)nB*KTOT + k*64 + lane] = (_Float16)(accB[k]*dB);
}

// ---------------------------------------------------------------- MFMA contraction: [NT x 1792] f16 x [1792 x 64] f16 -> out_sp f32
// wave = 16 nodes x 64 outputs (4 N-tiles); 56 K-chunks of 32.
__global__ __launch_bounds__(256) void k_gemm(
    const _Float16* __restrict__ accN,   // [NT][1792]
    const half8* __restrict__ wswz,      // [(chunk*4+tile)*64 + lane]
    const float* __restrict__ sp_bias,   // [64]
    float* __restrict__ out_sp)          // [NT][64]
{
  const int t = threadIdx.x, wid = t>>6, lane = t&63;
  const int n0 = blockIdx.x*64 + wid*16;     // grid 625 -> exact
  const int m = lane&15, kb = lane>>4;
  f32x4 d0 = {0,0,0,0}, d1 = {0,0,0,0}, d2 = {0,0,0,0}, d3 = {0,0,0,0};
  const _Float16* arow = accN + (size_t)(n0 + m)*KTOT + kb*8;
#pragma unroll 2
  for (int c=0; c<NCH; c++){
    const half8 a  = *(const half8*)(arow + c*32);
    const half8 b0 = wswz[(c*4+0)*64 + lane];
    const half8 b1 = wswz[(c*4+1)*64 + lane];
    const half8 b2 = wswz[(c*4+2)*64 + lane];
    const half8 b3 = wswz[(c*4+3)*64 + lane];
    d0 = __builtin_amdgcn_mfma_f32_16x16x32_f16(a, b0, d0, 0, 0, 0);
    d1 = __builtin_amdgcn_mfma_f32_16x16x32_f16(a, b1, d1, 0, 0, 0);
    d2 = __builtin_amdgcn_mfma_f32_16x16x32_f16(a, b2, d2, 0, 0, 0);
    d3 = __builtin_amdgcn_mfma_f32_16x16x32_f16(a, b3, d3, 0, 0, 0);
  }
  // D: row = kb*4 + r, col = tile*16 + m
  const float bb0 = sp_bias[ 0 + m], bb1 = sp_bias[16 + m];
  const float bb2 = sp_bias[32 + m], bb3 = sp_bias[48 + m];
#pragma unroll
  for (int r=0;r<4;r++){
    const size_t row = (size_t)(n0 + kb*4 + r)*64;
    out_sp[row +  0 + m] = eluf(d0[r] + bb0);
    out_sp[row + 16 + m] = eluf(d1[r] + bb1);
    out_sp[row + 32 + m] = eluf(d2[r] + bb2);
    out_sp[row + 48 + m] = eluf(d3[r] + bb3);
  }
}

// ---------------------------------------------------------------- decoder: out_sp[NT,64] -> out[NT,2]
__global__ __launch_bounds__(256) void k_decoder(
    const float* __restrict__ out_sp,
    const float* __restrict__ dw0, const float* __restrict__ db0,
    const float* __restrict__ dw1, const float* __restrict__ db1,
    const float* __restrict__ dw2, const float* __restrict__ db2,
    float* __restrict__ out)
{
  int n = blockIdx.x*256 + threadIdx.x;
  bool ok = n < NT;
  int nn = ok ? n : 0;
  float h[64];
#pragma unroll
  for (int q=0;q<16;q++){
    float4 v = *(const float4*)&out_sp[(size_t)nn*64 + 4*q];
    h[4*q+0]=v.x; h[4*q+1]=v.y; h[4*q+2]=v.z; h[4*q+3]=v.w;
  }
  float g[32];
#pragma unroll
  for (int o=0;o<32;o++){
    float a = db0[o];
#pragma unroll
    for (int c=0;c<64;c++) a = fmaf(dw0[o*64+c], h[c], a);
    g[o] = eluf(a);
  }
  float q16[16];
#pragma unroll
  for (int o=0;o<16;o++){
    float a = db1[o];
#pragma unroll
    for (int c=0;c<32;c++) a = fmaf(dw1[o*32+c], g[c], a);
    q16[o] = eluf(a);
  }
  float o0 = db2[0], o1 = db2[1];
#pragma unroll
  for (int c=0;c<16;c++){
    o0 = fmaf(dw2[c],    q16[c], o0);
    o1 = fmaf(dw2[16+c], q16[c], o1);
  }
  if (ok){
    float2 r; r.x = tanhf(o0); r.y = tanhf(o1);
    *(float2*)&out[(size_t)n*2] = r;
  }
}

// ---------------------------------------------------------------- launcher
extern "C" void kernel_launch(void* const* d_in, const int* in_sizes, int n_in,
                              void* d_out, int out_size, void* d_ws, size_t ws_size,
                              hipStream_t stream)
{
  const float* x    = (const float*)d_in[1];
  const int*   ei   = (const int*)  d_in[2];
  const float* attr = (const float*)d_in[3];
  const float* ew0  = (const float*)d_in[4];  const float* eb0 = (const float*)d_in[5];
  const float* ew1  = (const float*)d_in[6];  const float* eb1 = (const float*)d_in[7];
  const float* ew2  = (const float*)d_in[8];  const float* eb2 = (const float*)d_in[9];
  const float* spw  = (const float*)d_in[10];
  const float* spr  = (const float*)d_in[11];
  const float* spb  = (const float*)d_in[12];
  const float* dw0  = (const float*)d_in[13]; const float* db0 = (const float*)d_in[14];
  const float* dw1  = (const float*)d_in[15]; const float* db1 = (const float*)d_in[16];
  const float* dw2  = (const float*)d_in[17]; const float* db2 = (const float*)d_in[18];
  float* out = (float*)d_out;

  char* p = (char*)d_ws;
  auto alloc = [&](size_t bytes)->char* {
    char* r = p; p += (bytes + 255) & ~size_t(255); return r;
  };
  float*    h_flat  = (float*)   alloc((size_t)NT*64*4);      // 10.24 MB
  float*    out_sp  = (float*)   alloc((size_t)NT*64*4);      // 10.24 MB
  _Float16* accN    = (_Float16*)alloc((size_t)NT*KTOT*2);    // 143.36 MB
  float4*   meta    = (float4*)  alloc((size_t)EDG*16);       // 10.24 MB
  int*      pkarr   = (int*)     alloc((size_t)EDG*4);        //  2.56 MB
  half8*    wswz    = (half8*)   alloc((size_t)NCH*4*64*16);  //  0.23 MB
  int*      rowptr  = (int*)     alloc((size_t)(NT+1)*4);
  int*      deg     = (int*)     alloc((size_t)NT*4);
  int*      cursor  = (int*)     alloc((size_t)NT*4);
  float*    deg_inv = (float*)   alloc((size_t)NT*4);
  int*      bsum    = (int*)     alloc((size_t)64*4);
  int*      boffs   = (int*)     alloc((size_t)64*4);

  k_init   <<<(NT+255)/256,  256, 0, stream>>>(deg, cursor);
  k_encoder<<<(NT+255)/256,  256, 0, stream>>>(x, ew0,eb0, ew1,eb1, ew2,eb2, h_flat, accN);
  k_count  <<<(EDG+255)/256, 256, 0, stream>>>(ei, deg);
  k_scanA  <<<40, 256, 0, stream>>>(deg, bsum);
  k_scanB  <<<1,  64,  0, stream>>>(bsum, boffs, rowptr);
  k_scanC  <<<40, 256, 0, stream>>>(deg, boffs, rowptr, deg_inv);
  k_fill   <<<(EDG+255)/256, 256, 0, stream>>>(ei, attr, rowptr, cursor, meta, pkarr);
  k_prep   <<<NCH, 256, 0, stream>>>(spw, spr, wswz);
  k_gather <<<NT/8,  256, 0, stream>>>(meta, pkarr, rowptr, deg_inv, h_flat, accN);
  k_gemm   <<<NT/64, 256, 0, stream>>>(accN, wswz, spb, out_sp);
  k_decoder<<<(NT+255)/256, 256, 0, stream>>>(out_sp, dw0,db0, dw1,db1, dw2,db2, out);
}

// Round 9
// 413.136 us; speedup vs baseline: 4.6087x; 1.2659x over previous
//
#include <hip/hip_runtime.h>
#include <hip/hip_fp16.h>
#include <math.h>

#define NT  40000   // total nodes (N*V)
#define EDG 640000  // edges
#define KTOT 1792   // 1728 spline + 64 root
#define NCH  56     // K chunks of 32

typedef _Float16 half8 __attribute__((ext_vector_type(8)));
typedef float    f32x4 __attribute__((ext_vector_type(4)));

__device__ __forceinline__ float eluf(float v){ return v > 0.f ? v : expm1f(v); }

// ---------------------------------------------------------------- init: zero deg
__global__ void k_init(int* __restrict__ deg){
  int i = blockIdx.x*256 + threadIdx.x;
  if (i < NT) deg[i] = 0;
}

// ---------------------------------------------------------------- encoder: x[NT,2] -> h_flat[NT,64] f32
__global__ __launch_bounds__(256) void k_encoder(
    const float* __restrict__ x,
    const float* __restrict__ w0, const float* __restrict__ b0,
    const float* __restrict__ w1, const float* __restrict__ b1,
    const float* __restrict__ w2, const float* __restrict__ b2,
    float* __restrict__ h_flat)
{
  int n = blockIdx.x*256 + threadIdx.x;
  bool ok = n < NT;
  int nn = ok ? n : 0;
  float x0 = x[(size_t)nn*2+0], x1 = x[(size_t)nn*2+1];
  float h1[16];
#pragma unroll
  for (int o=0;o<16;o++) h1[o] = eluf(b0[o] + w0[o*2+0]*x0 + w0[o*2+1]*x1);
  float h2[32];
#pragma unroll
  for (int o=0;o<32;o++){
    float a = b1[o];
#pragma unroll
    for (int c=0;c<16;c++) a = fmaf(w1[o*16+c], h1[c], a);
    h2[o] = eluf(a);
  }
#pragma unroll
  for (int o=0;o<64;o++){
    float a = b2[o];
#pragma unroll
    for (int c=0;c<32;c++) a = fmaf(w2[o*32+c], h2[c], a);
    if (ok) h_flat[(size_t)n*64+o] = eluf(a);
  }
}

// ---------------------------------------------------------------- degree count
__global__ void k_count(const int* __restrict__ ei, int* __restrict__ deg){
  int e = blockIdx.x*256 + threadIdx.x;
  if (e < EDG) atomicAdd(&deg[ei[EDG+e]], 1);
}

// ---------------------------------------------------------------- parallel scan (3 kernels, 40 blocks of 1024)
__global__ void k_scanA(const int* __restrict__ deg, int* __restrict__ bsum){
  __shared__ int sm[256];
  const int t = threadIdx.x, b = blockIdx.x;
  const int base = b*1024 + t*4;
  int s = 0;
#pragma unroll
  for (int i=0;i<4;i++){ int idx = base+i; if (idx < NT) s += deg[idx]; }
  sm[t] = s; __syncthreads();
  for (int off=128; off>0; off>>=1){ if (t < off) sm[t] += sm[t+off]; __syncthreads(); }
  if (t == 0) bsum[b] = sm[0];
}
__global__ void k_scanB(const int* __restrict__ bsum, int* __restrict__ boffs,
                        int* __restrict__ rowptr){
  if (threadIdx.x == 0){
    int run = 0;
    for (int i=0;i<40;i++){ boffs[i] = run; run += bsum[i]; }
    rowptr[NT] = run;
  }
}
__global__ void k_scanC(const int* __restrict__ deg, const int* __restrict__ boffs,
                        int* __restrict__ rowptr, int* __restrict__ cursor,
                        float* __restrict__ deg_inv){
  __shared__ int sm[256];
  const int t = threadIdx.x, b = blockIdx.x;
  const int base = b*1024 + t*4;
  int v[4]; int s = 0;
#pragma unroll
  for (int i=0;i<4;i++){ int idx = base+i; v[i] = (idx < NT) ? deg[idx] : 0; s += v[i]; }
  sm[t] = s; __syncthreads();
  for (int off=1; off<256; off<<=1){
    int u = (t >= off) ? sm[t-off] : 0;
    __syncthreads();
    sm[t] += u;
    __syncthreads();
  }
  int excl = sm[t] - s + boffs[b];
#pragma unroll
  for (int i=0;i<4;i++){
    int idx = base+i;
    if (idx < NT){
      rowptr[idx] = excl;
      cursor[idx] = excl;     // fill's atomic cursor starts at row base
      deg_inv[idx] = 1.0f / fmaxf((float)v[i], 1.0f);
      excl += v[i];
    }
  }
}

// ---------------------------------------------------------------- CSR fill: meta = {f0,f1,f2, bits(src<<3|k0pack)}
__global__ void k_fill(const int* __restrict__ ei, const float* __restrict__ attr,
                       int* __restrict__ cursor, float4* __restrict__ meta)
{
  int e = blockIdx.x*256 + threadIdx.x;
  if (e >= EDG) return;
  int src = ei[e], dst = ei[EDG+e];
  float v0 = attr[(size_t)e*3+0]*2.f, v1 = attr[(size_t)e*3+1]*2.f, v2 = attr[(size_t)e*3+2]*2.f;
  float k00 = fminf(fmaxf(floorf(v0), 0.f), 1.f);
  float k01 = fminf(fmaxf(floorf(v1), 0.f), 1.f);
  float k02 = fminf(fmaxf(floorf(v2), 0.f), 1.f);
  int kp = ((int)k00)*4 + ((int)k01)*2 + (int)k02;
  float f0 = v0-k00, f1 = v1-k01, f2 = v2-k02;
  int pos = atomicAdd(&cursor[dst], 1);
  meta[pos] = make_float4(f0, f1, f2, __int_as_float((src<<3) | kp));
}

// ---------------------------------------------------------------- W pre-swizzle into MFMA B-frag order (fp16)
__global__ __launch_bounds__(256) void k_prep(
    const float* __restrict__ sp_w,      // [1728][64]
    const float* __restrict__ sp_root,   // [64][64]
    half8* __restrict__ wswz)
{
  const int t = threadIdx.x, c = blockIdx.x;      // grid 56
  const int tile = t>>6, lane = t&63;
  const int kb = lane>>4, col = tile*16 + (lane&15);
  half8 h;
#pragma unroll
  for (int j=0;j<8;j++){
    const int k = c*32 + kb*8 + j;
    const float v = (k < 1728) ? sp_w[(size_t)k*64 + col] : sp_root[(size_t)(k-1728)*64 + col];
    h[j] = (_Float16)v;
  }
  wswz[(c*4 + tile)*64 + lane] = h;
}

// ---------------------------------------------------------------- gather: 1 node/wave, scalar (SMEM) meta path, 3-stage prefetch
// acc[27] in VGPRs; per edge: s_load meta (broadcast), x_j vector load, 17 VALU, scalar switch.
__global__ __launch_bounds__(256) void k_gather(
    const float4* __restrict__ meta,
    const int* __restrict__ rowptr,
    const float* __restrict__ deg_inv,
    const float* __restrict__ h_flat,
    _Float16* __restrict__ accN)          // [NT][1792]
{
  const int lane = threadIdx.x & 63;
  const int ns = __builtin_amdgcn_readfirstlane(blockIdx.x*4 + (threadIdx.x>>6));
  float acc[27];
#pragma unroll
  for (int k=0;k<27;k++) acc[k] = 0.f;
  const int beg = rowptr[ns], end = rowptr[ns+1];
  const int deg = end - beg;

#define EDGE(mm, pk, xj) { \
  const float u0 = 1.f-(mm).x, u1 = 1.f-(mm).y, u2 = 1.f-(mm).z; \
  const float t0 = u0*(xj), t1 = (mm).x*(xj); \
  const float p00 = u1*u2, p01 = u1*(mm).z, p10 = (mm).y*u2, p11 = (mm).y*(mm).z; \
  switch ((pk) & 7){ \
    case 0: { DO_CASE(0)  } break; \
    case 1: { DO_CASE(1)  } break; \
    case 2: { DO_CASE(3)  } break; \
    case 3: { DO_CASE(4)  } break; \
    case 4: { DO_CASE(9)  } break; \
    case 5: { DO_CASE(10) } break; \
    case 6: { DO_CASE(12) } break; \
    case 7: { DO_CASE(13) } break; \
  } }
#define DO_CASE(B) \
  acc[(B)+0]  = fmaf(p00,t0,acc[(B)+0]);  \
  acc[(B)+1]  = fmaf(p01,t0,acc[(B)+1]);  \
  acc[(B)+3]  = fmaf(p10,t0,acc[(B)+3]);  \
  acc[(B)+4]  = fmaf(p11,t0,acc[(B)+4]);  \
  acc[(B)+9]  = fmaf(p00,t1,acc[(B)+9]);  \
  acc[(B)+10] = fmaf(p01,t1,acc[(B)+10]); \
  acc[(B)+12] = fmaf(p10,t1,acc[(B)+12]); \
  acc[(B)+13] = fmaf(p11,t1,acc[(B)+13]);

  float4 m0, m1;
  int pk0 = 0, pk1 = 0;
  float x0 = 0.f, x1 = 0.f;
  if (deg > 0){
    m0  = meta[beg];
    pk0 = __builtin_amdgcn_readfirstlane(__float_as_int(m0.w));
    x0  = h_flat[(size_t)(pk0>>3)*64 + lane];
  }
  if (deg > 1){
    m1  = meta[beg+1];
    pk1 = __builtin_amdgcn_readfirstlane(__float_as_int(m1.w));
    x1  = h_flat[(size_t)(pk1>>3)*64 + lane];
  }
  int j = 0;
  for (; j + 2 < deg; j++){
    const float4 m2 = meta[beg+j+2];              // prefetch (scalar load, in flight over EDGE)
    EDGE(m0, pk0, x0)
    const int   pk2 = __builtin_amdgcn_readfirstlane(__float_as_int(m2.w));
    const float x2  = h_flat[(size_t)(pk2>>3)*64 + lane];   // in flight over next EDGE
    m0 = m1; pk0 = pk1; x0 = x1;
    m1 = m2; pk1 = pk2; x1 = x2;
  }
  if (j < deg){ EDGE(m0, pk0, x0) j++; }
  if (j < deg){ EDGE(m1, pk1, x1) }
#undef DO_CASE
#undef EDGE

  const float dinv = deg_inv[ns];
  _Float16* arow = accN + (size_t)ns*KTOT;
#pragma unroll
  for (int k=0;k<27;k++)
    arow[k*64 + lane] = (_Float16)(acc[k]*dinv);
  // root column block (contiguous 128B per node; avoids encoder's 32x write-amplification)
  arow[1728 + lane] = (_Float16)h_flat[(size_t)ns*64 + lane];
}

// ---------------------------------------------------------------- MFMA contraction: [NT x 1792] f16 x [1792 x 64] f16 -> out_sp f32
__global__ __launch_bounds__(256) void k_gemm(
    const _Float16* __restrict__ accN,   // [NT][1792]
    const half8* __restrict__ wswz,      // [(chunk*4+tile)*64 + lane]
    const float* __restrict__ sp_bias,   // [64]
    float* __restrict__ out_sp)          // [NT][64]
{
  const int t = threadIdx.x, wid = t>>6, lane = t&63;
  const int n0 = blockIdx.x*64 + wid*16;     // grid 625 -> exact
  const int m = lane&15, kb = lane>>4;
  f32x4 d0 = {0,0,0,0}, d1 = {0,0,0,0}, d2 = {0,0,0,0}, d3 = {0,0,0,0};
  const _Float16* arow = accN + (size_t)(n0 + m)*KTOT + kb*8;
#pragma unroll 2
  for (int c=0; c<NCH; c++){
    const half8 a  = *(const half8*)(arow + c*32);
    const half8 b0 = wswz[(c*4+0)*64 + lane];
    const half8 b1 = wswz[(c*4+1)*64 + lane];
    const half8 b2 = wswz[(c*4+2)*64 + lane];
    const half8 b3 = wswz[(c*4+3)*64 + lane];
    d0 = __builtin_amdgcn_mfma_f32_16x16x32_f16(a, b0, d0, 0, 0, 0);
    d1 = __builtin_amdgcn_mfma_f32_16x16x32_f16(a, b1, d1, 0, 0, 0);
    d2 = __builtin_amdgcn_mfma_f32_16x16x32_f16(a, b2, d2, 0, 0, 0);
    d3 = __builtin_amdgcn_mfma_f32_16x16x32_f16(a, b3, d3, 0, 0, 0);
  }
  // D: row = kb*4 + r, col = tile*16 + m
  const float bb0 = sp_bias[ 0 + m], bb1 = sp_bias[16 + m];
  const float bb2 = sp_bias[32 + m], bb3 = sp_bias[48 + m];
#pragma unroll
  for (int r=0;r<4;r++){
    const size_t row = (size_t)(n0 + kb*4 + r)*64;
    out_sp[row +  0 + m] = eluf(d0[r] + bb0);
    out_sp[row + 16 + m] = eluf(d1[r] + bb1);
    out_sp[row + 32 + m] = eluf(d2[r] + bb2);
    out_sp[row + 48 + m] = eluf(d3[r] + bb3);
  }
}

// ---------------------------------------------------------------- decoder: out_sp[NT,64] -> out[NT,2]
__global__ __launch_bounds__(256) void k_decoder(
    const float* __restrict__ out_sp,
    const float* __restrict__ dw0, const float* __restrict__ db0,
    const float* __restrict__ dw1, const float* __restrict__ db1,
    const float* __restrict__ dw2, const float* __restrict__ db2,
    float* __restrict__ out)
{
  int n = blockIdx.x*256 + threadIdx.x;
  bool ok = n < NT;
  int nn = ok ? n : 0;
  float h[64];
#pragma unroll
  for (int q=0;q<16;q++){
    float4 v = *(const float4*)&out_sp[(size_t)nn*64 + 4*q];
    h[4*q+0]=v.x; h[4*q+1]=v.y; h[4*q+2]=v.z; h[4*q+3]=v.w;
  }
  float g[32];
#pragma unroll
  for (int o=0;o<32;o++){
    float a = db0[o];
#pragma unroll
    for (int c=0;c<64;c++) a = fmaf(dw0[o*64+c], h[c], a);
    g[o] = eluf(a);
  }
  float q16[16];
#pragma unroll
  for (int o=0;o<16;o++){
    float a = db1[o];
#pragma unroll
    for (int c=0;c<32;c++) a = fmaf(dw1[o*32+c], g[c], a);
    q16[o] = eluf(a);
  }
  float o0 = db2[0], o1 = db2[1];
#pragma unroll
  for (int c=0;c<16;c++){
    o0 = fmaf(dw2[c],    q16[c], o0);
    o1 = fmaf(dw2[16+c], q16[c], o1);
  }
  if (ok){
    float2 r; r.x = tanhf(o0); r.y = tanhf(o1);
    *(float2*)&out[(size_t)n*2] = r;
  }
}

// ---------------------------------------------------------------- launcher
extern "C" void kernel_launch(void* const* d_in, const int* in_sizes, int n_in,
                              void* d_out, int out_size, void* d_ws, size_t ws_size,
                              hipStream_t stream)
{
  const float* x    = (const float*)d_in[1];
  const int*   ei   = (const int*)  d_in[2];
  const float* attr = (const float*)d_in[3];
  const float* ew0  = (const float*)d_in[4];  const float* eb0 = (const float*)d_in[5];
  const float* ew1  = (const float*)d_in[6];  const float* eb1 = (const float*)d_in[7];
  const float* ew2  = (const float*)d_in[8];  const float* eb2 = (const float*)d_in[9];
  const float* spw  = (const float*)d_in[10];
  const float* spr  = (const float*)d_in[11];
  const float* spb  = (const float*)d_in[12];
  const float* dw0  = (const float*)d_in[13]; const float* db0 = (const float*)d_in[14];
  const float* dw1  = (const float*)d_in[15]; const float* db1 = (const float*)d_in[16];
  const float* dw2  = (const float*)d_in[17]; const float* db2 = (const float*)d_in[18];
  float* out = (float*)d_out;

  char* p = (char*)d_ws;
  auto alloc = [&](size_t bytes)->char* {
    char* r = p; p += (bytes + 255) & ~size_t(255); return r;
  };
  float*    h_flat  = (float*)   alloc((size_t)NT*64*4);      // 10.24 MB
  float*    out_sp  = (float*)   alloc((size_t)NT*64*4);      // 10.24 MB
  _Float16* accN    = (_Float16*)alloc((size_t)NT*KTOT*2);    // 143.36 MB
  float4*   meta    = (float4*)  alloc((size_t)EDG*16);       // 10.24 MB
  half8*    wswz    = (half8*)   alloc((size_t)NCH*4*64*16);  //  0.23 MB
  int*      rowptr  = (int*)     alloc((size_t)(NT+1)*4);
  int*      deg     = (int*)     alloc((size_t)NT*4);
  int*      cursor  = (int*)     alloc((size_t)NT*4);
  float*    deg_inv = (float*)   alloc((size_t)NT*4);
  int*      bsum    = (int*)     alloc((size_t)64*4);
  int*      boffs   = (int*)     alloc((size_t)64*4);

  k_init   <<<(NT+255)/256,  256, 0, stream>>>(deg);
  k_encoder<<<(NT+255)/256,  256, 0, stream>>>(x, ew0,eb0, ew1,eb1, ew2,eb2, h_flat);
  k_count  <<<(EDG+255)/256, 256, 0, stream>>>(ei, deg);
  k_scanA  <<<40, 256, 0, stream>>>(deg, bsum);
  k_scanB  <<<1,  64,  0, stream>>>(bsum, boffs, rowptr);
  k_scanC  <<<40, 256, 0, stream>>>(deg, boffs, rowptr, cursor, deg_inv);
  k_fill   <<<(EDG+255)/256, 256, 0, stream>>>(ei, attr, cursor, meta);
  k_prep   <<<NCH, 256, 0, stream>>>(spw, spr, wswz);
  k_gather <<<NT/4,  256, 0, stream>>>(meta, rowptr, deg_inv, h_flat, accN);
  k_gemm   <<<NT/64, 256, 0, stream>>>(accN, wswz, spb, out_sp);
  k_decoder<<<(NT+255)/256, 256, 0, stream>>>(out_sp, dw0,db0, dw1,db1, dw2,db2, out);
}